// Round 4
// baseline (78.094 us; speedup 1.0000x reference)
//
#include <hip/hip_runtime.h>

#define HW   4096      // 64*64
#define NC   256
#define NTB  24        // 3 tensors * 8 batches
#define TOPK 2048      // max(1, int(0.5 * 4096))

typedef float  vf4 __attribute__((ext_vector_type(4)));   // native vec: ok for nontemporal builtins
typedef float  vf2 __attribute__((ext_vector_type(2)));

// ---------------------------------------------------------------------------
// Pass A: imp[tb][hw] = (sum_{c=0..255, strictly sequential} |x[tb][c][hw]|) / 256
// Sequential single-accumulator per hw chain == numpy reduce order (bitwise).
// 2 chains per thread via float2 loads; unroll-16 keeps 128 B/lane in flight.
// ---------------------------------------------------------------------------
__global__ __launch_bounds__(256) void k_imp(const float* __restrict__ i0,
                                             const float* __restrict__ i1,
                                             const float* __restrict__ i2,
                                             float* __restrict__ imp) {
  int tid = blockIdx.x * 256 + threadIdx.x;   // 0 .. 49151
  int hw2 = tid & (HW / 2 - 1);               // float2 index within row
  int tb  = tid >> 11;                        // 0 .. 23
  int t   = tb >> 3;
  const float* base = (t == 0 ? i0 : (t == 1 ? i1 : i2));
  const vf2* p = reinterpret_cast<const vf2*>(base + (size_t)(tb & 7) * NC * HW) + hw2;
  float s0 = 0.f, s1 = 0.f;
#pragma unroll 16
  for (int c = 0; c < NC; ++c) {
    vf2 v = p[c * (HW / 2)];
    s0 += fabsf(v.x);                         // program order preserved per chain
    s1 += fabsf(v.y);
  }
  vf2 m;
  m.x = s0 * (1.0f / 256.0f);                 // exact pow2 scale == /256.0
  m.y = s1 * (1.0f / 256.0f);
  reinterpret_cast<vf2*>(imp)[tid] = m;
}

// ---------------------------------------------------------------------------
// Pass B: ONE WAVE per (tensor,batch) row. All 4096 values live in registers
// (64 per lane, lane l holds hw [l*64, l*64+64) -> lane-chunk order == index
// order). Binary search k-th largest on uint bits (all imp >= 0 so uint
// compare == float compare); min/max prescan narrows the range to ~20 iters.
// No __syncthreads anywhere. Stable-top_k ties: lowest indices win.
// Mask (0/1 floats) overwrites imp in place.
// ---------------------------------------------------------------------------
__global__ __launch_bounds__(64) void k_select(float* __restrict__ impmask) {
  const int tb   = blockIdx.x;
  float* base    = impmask + (size_t)tb * HW;
  const int lane = threadIdx.x;

  unsigned u[64];
  const vf4* p = reinterpret_cast<const vf4*>(base + lane * 64);
#pragma unroll
  for (int j = 0; j < 16; ++j) {
    vf4 v = p[j];
    u[4 * j + 0] = __float_as_uint(v.x);
    u[4 * j + 1] = __float_as_uint(v.y);
    u[4 * j + 2] = __float_as_uint(v.z);
    u[4 * j + 3] = __float_as_uint(v.w);
  }

  // prescan: tight initial [lo, hi) from actual min/max
  unsigned mx = 0u, mn = 0xFFFFFFFFu;
#pragma unroll
  for (int j = 0; j < 64; ++j) {
    mx = (u[j] > mx) ? u[j] : mx;
    mn = (u[j] < mn) ? u[j] : mn;
  }
#pragma unroll
  for (int off = 32; off > 0; off >>= 1) {
    unsigned ox = (unsigned)__shfl_xor((int)mx, off, 64);
    unsigned on = (unsigned)__shfl_xor((int)mn, off, 64);
    mx = (ox > mx) ? ox : mx;
    mn = (on < mn) ? on : mn;
  }

  // invariant: cnt_ge(lo) >= K  (lo=min -> 4096), cnt_ge(hi) < K (hi=max+1 -> 0)
  unsigned lo = mn, hi = mx + 1u;
  while (hi - lo > 1u) {
    unsigned mid = lo + ((hi - lo) >> 1);
    int c = 0;
#pragma unroll
    for (int j = 0; j < 64; ++j) c += (u[j] >= mid);
#pragma unroll
    for (int off = 32; off > 0; off >>= 1) c += __shfl_xor(c, off, 64);
    if (c >= TOPK) lo = mid; else hi = mid;   // c uniform across lanes
  }
  const unsigned thr = lo;                    // bits of the k-th largest value

  int eq = 0, gt = 0;
#pragma unroll
  for (int j = 0; j < 64; ++j) {
    eq += (u[j] == thr);
    gt += (u[j] > thr);
  }
  int g_tot = gt;
#pragma unroll
  for (int off = 32; off > 0; off >>= 1) g_tot += __shfl_xor(g_tot, off, 64);

  // exclusive prefix of eq-counts across lanes (lane order == index order)
  int incl = eq;
#pragma unroll
  for (int off = 1; off < 64; off <<= 1) {
    int n = __shfl_up(incl, off, 64);
    if (lane >= off) incl += n;
  }
  int r = incl - eq;                          // this lane's starting tie-rank
  const int needed = TOPK - g_tot;            // how many tied values to keep

  vf4* q = reinterpret_cast<vf4*>(base + lane * 64);
#pragma unroll
  for (int j = 0; j < 16; ++j) {
    float mv[4];
#pragma unroll
    for (int s = 0; s < 4; ++s) {
      unsigned x = u[4 * j + s];
      int e = (x == thr);
      mv[s] = (x > thr || (e && r < needed)) ? 1.f : 0.f;
      r += e;
    }
    vf4 m;
    m.x = mv[0]; m.y = mv[1]; m.z = mv[2]; m.w = mv[3];
    q[j] = m;
  }
}

// ---------------------------------------------------------------------------
// Pass C: out = in * mask. GRID-STRIDE: 2048 blocks x 256 thr (8 blocks/CU,
// full occupancy), 12 vf4/thread in 3 batches of 4 independent loads (64 B
// in flight per lane) instead of 24576 one-shot blocks (block churn +
// dispatch ramp + zero ILP). Input loads nontemporal (no reuse after this);
// mask loads cached (384 KB, reused across all c-planes); output stores
// nontemporal (don't evict L3-resident input via write-allocate).
// ---------------------------------------------------------------------------
#define APPLY_BLOCKS 2048
#define APPLY_STRIDE (APPLY_BLOCKS * 256)
__global__ __launch_bounds__(256) void k_apply(const vf4* __restrict__ i0,
                                               const vf4* __restrict__ i1,
                                               const vf4* __restrict__ i2,
                                               const vf4* __restrict__ mask,
                                               vf4* __restrict__ out) {
  const int base_idx = blockIdx.x * 256 + threadIdx.x;
  // total vf4 = 24*256*1024 = 6291456 = APPLY_STRIDE * 12 exactly
#pragma unroll
  for (int it = 0; it < 3; ++it) {
    int idx[4];
    vf4 a[4], m[4];
#pragma unroll
    for (int q = 0; q < 4; ++q) {
      int i = base_idx + (it * 4 + q) * APPLY_STRIDE;
      idx[q] = i;
      int tb = i >> 18;                       // 2^18 vf4 per (t,b)
      int t  = tb >> 3;
      const vf4* src = (t == 0 ? i0 : (t == 1 ? i1 : i2));
      a[q] = __builtin_nontemporal_load(&src[i - (t << 21)]);  // 2^21 vf4/tensor
      m[q] = mask[(tb << 10) | (i & 1023)];
    }
#pragma unroll
    for (int q = 0; q < 4; ++q) {
      vf4 r = a[q] * m[q];
      __builtin_nontemporal_store(r, &out[idx[q]]);
    }
  }
}

extern "C" void kernel_launch(void* const* d_in, const int* in_sizes, int n_in,
                              void* d_out, int out_size, void* d_ws, size_t ws_size,
                              hipStream_t stream) {
  const float* i0 = (const float*)d_in[0];
  const float* i1 = (const float*)d_in[1];
  const float* i2 = (const float*)d_in[2];
  float* imp = (float*)d_ws;   // 3*8*4096 floats = 384 KB of scratch

  k_imp<<<192, 256, 0, stream>>>(i0, i1, i2, imp);
  k_select<<<NTB, 64, 0, stream>>>(imp);
  k_apply<<<APPLY_BLOCKS, 256, 0, stream>>>((const vf4*)i0, (const vf4*)i1,
                                            (const vf4*)i2, (const vf4*)imp,
                                            (vf4*)d_out);
}

// Round 5
// 71.657 us; speedup vs baseline: 1.0898x; 1.0898x over previous
//
#include <hip/hip_runtime.h>

#define HW   4096      // 64*64
#define NC   256
#define NTB  24        // 3 tensors * 8 batches
#define TOPK 2048      // max(1, int(0.5 * 4096))

typedef float  vf4 __attribute__((ext_vector_type(4)));   // native vec: ok for nontemporal builtins
typedef float  vf2 __attribute__((ext_vector_type(2)));

// ---------------------------------------------------------------------------
// Pass A: imp[tb][hw] = (sum_{c=0..255, strictly sequential} |x[tb][c][hw]|) / 256
// ONE scalar chain per thread (bitwise == numpy reduce order: same c order,
// same add sequence). 98304 threads -> 384 blocks x 256 (all 256 CUs, 6
// waves/CU, vs previous 192 blocks / 0.75 blocks/CU). unroll-32 keeps 32
// independent 4 B loads in flight per lane (128 B/lane, ~12.6 MB chip-wide).
// ---------------------------------------------------------------------------
__global__ __launch_bounds__(256) void k_imp(const float* __restrict__ i0,
                                             const float* __restrict__ i1,
                                             const float* __restrict__ i2,
                                             float* __restrict__ imp) {
  int tid = blockIdx.x * 256 + threadIdx.x;   // 0 .. 98303
  int hw  = tid & (HW - 1);
  int tb  = tid >> 12;                        // 0 .. 23
  int t   = tb >> 3;
  const float* base = (t == 0 ? i0 : (t == 1 ? i1 : i2));
  const float* p = base + (size_t)(tb & 7) * NC * HW + hw;
  float s = 0.f;
#pragma unroll 32
  for (int c = 0; c < NC; ++c) {
    s += fabsf(p[c * HW]);                    // program order preserved per chain
  }
  imp[tid] = s * (1.0f / 256.0f);             // exact pow2 scale == /256.0
}

// ---------------------------------------------------------------------------
// Pass B: ONE WAVE per (tensor,batch) row. All 4096 values live in registers
// (64 per lane, lane l holds hw [l*64, l*64+64) -> lane-chunk order == index
// order). Binary search k-th largest on uint bits (all imp >= 0 so uint
// compare == float compare); min/max prescan narrows the range to ~20 iters.
// No __syncthreads anywhere. Stable-top_k ties: lowest indices win.
// Mask (0/1 floats) overwrites imp in place.
// ---------------------------------------------------------------------------
__global__ __launch_bounds__(64) void k_select(float* __restrict__ impmask) {
  const int tb   = blockIdx.x;
  float* base    = impmask + (size_t)tb * HW;
  const int lane = threadIdx.x;

  unsigned u[64];
  const vf4* p = reinterpret_cast<const vf4*>(base + lane * 64);
#pragma unroll
  for (int j = 0; j < 16; ++j) {
    vf4 v = p[j];
    u[4 * j + 0] = __float_as_uint(v.x);
    u[4 * j + 1] = __float_as_uint(v.y);
    u[4 * j + 2] = __float_as_uint(v.z);
    u[4 * j + 3] = __float_as_uint(v.w);
  }

  // prescan: tight initial [lo, hi) from actual min/max
  unsigned mx = 0u, mn = 0xFFFFFFFFu;
#pragma unroll
  for (int j = 0; j < 64; ++j) {
    mx = (u[j] > mx) ? u[j] : mx;
    mn = (u[j] < mn) ? u[j] : mn;
  }
#pragma unroll
  for (int off = 32; off > 0; off >>= 1) {
    unsigned ox = (unsigned)__shfl_xor((int)mx, off, 64);
    unsigned on = (unsigned)__shfl_xor((int)mn, off, 64);
    mx = (ox > mx) ? ox : mx;
    mn = (on < mn) ? on : mn;
  }

  // invariant: cnt_ge(lo) >= K  (lo=min -> 4096), cnt_ge(hi) < K (hi=max+1 -> 0)
  unsigned lo = mn, hi = mx + 1u;
  while (hi - lo > 1u) {
    unsigned mid = lo + ((hi - lo) >> 1);
    int c = 0;
#pragma unroll
    for (int j = 0; j < 64; ++j) c += (u[j] >= mid);
#pragma unroll
    for (int off = 32; off > 0; off >>= 1) c += __shfl_xor(c, off, 64);
    if (c >= TOPK) lo = mid; else hi = mid;   // c uniform across lanes
  }
  const unsigned thr = lo;                    // bits of the k-th largest value

  int eq = 0, gt = 0;
#pragma unroll
  for (int j = 0; j < 64; ++j) {
    eq += (u[j] == thr);
    gt += (u[j] > thr);
  }
  int g_tot = gt;
#pragma unroll
  for (int off = 32; off > 0; off >>= 1) g_tot += __shfl_xor(g_tot, off, 64);

  // exclusive prefix of eq-counts across lanes (lane order == index order)
  int incl = eq;
#pragma unroll
  for (int off = 1; off < 64; off <<= 1) {
    int n = __shfl_up(incl, off, 64);
    if (lane >= off) incl += n;
  }
  int r = incl - eq;                          // this lane's starting tie-rank
  const int needed = TOPK - g_tot;            // how many tied values to keep

  vf4* q = reinterpret_cast<vf4*>(base + lane * 64);
#pragma unroll
  for (int j = 0; j < 16; ++j) {
    float mv[4];
#pragma unroll
    for (int s = 0; s < 4; ++s) {
      unsigned x = u[4 * j + s];
      int e = (x == thr);
      mv[s] = (x > thr || (e && r < needed)) ? 1.f : 0.f;
      r += e;
    }
    vf4 m;
    m.x = mv[0]; m.y = mv[1]; m.z = mv[2]; m.w = mv[3];
    q[j] = m;
  }
}

// ---------------------------------------------------------------------------
// Pass C: out = in * mask (vf4 per thread). Mask tile is 16 KB/(t,b) ->
// cached; input re-read hits L3 (96 MB < 256 MB, proven by R4's nt-load
// regression). Nontemporal output stores only.
// ---------------------------------------------------------------------------
__global__ __launch_bounds__(256) void k_apply(const vf4* __restrict__ i0,
                                               const vf4* __restrict__ i1,
                                               const vf4* __restrict__ i2,
                                               const vf4* __restrict__ mask,
                                               vf4* __restrict__ out) {
  int i = blockIdx.x * 256 + threadIdx.x;   // 0 .. 6291455 (vf4 units)
  int hw4 = i & 1023;                        // vf4 col within row
  int tb  = i >> 18;                         // (t*8 + b); 2^18 vf4 per (t,b)
  int t   = tb >> 3;
  const vf4* src = (t == 0 ? i0 : (t == 1 ? i1 : i2));
  vf4 a = src[i - (t << 21)];                // 2^21 vf4 per tensor
  vf4 m = mask[(tb << 10) | hw4];
  vf4 r = a * m;
  __builtin_nontemporal_store(r, &out[i]);
}

extern "C" void kernel_launch(void* const* d_in, const int* in_sizes, int n_in,
                              void* d_out, int out_size, void* d_ws, size_t ws_size,
                              hipStream_t stream) {
  const float* i0 = (const float*)d_in[0];
  const float* i1 = (const float*)d_in[1];
  const float* i2 = (const float*)d_in[2];
  float* imp = (float*)d_ws;   // 3*8*4096 floats = 384 KB of scratch

  k_imp<<<384, 256, 0, stream>>>(i0, i1, i2, imp);
  k_select<<<NTB, 64, 0, stream>>>(imp);
  k_apply<<<24576, 256, 0, stream>>>((const vf4*)i0, (const vf4*)i1,
                                     (const vf4*)i2, (const vf4*)imp,
                                     (vf4*)d_out);
}